// Round 3
// baseline (174.170 us; speedup 1.0000x reference)
//
#include <hip/hip_runtime.h>

// EmbeddingShard: out[n, :] = (W_full[tok[n], :] + sum_s b[s, :]) / SHARDS
// tok: [32768] int32, W: [8, 6300, 4096] f32 (contiguous == W_full [50400,4096]),
// b: [8, 4096] f32, out: [32768, 4096] f32.
// Memory-bound gather: ~537 MB streamed NT write + ~390-537 MB gather read.
// R3: 16 contiguous rows per block, all ids preloaded to LDS (no per-iteration
// id->gather dependency); 2-row body keeps VGPR <= 64 for 32 waves/CU.

#define OUT_DIM 4096
#define SHARDS 8
#define ROWS_PER_BLOCK 16

typedef float f32x4 __attribute__((ext_vector_type(4)));

// Step 1: bsum[j] = (sum_s b[s][j]) * 0.125  (pre-scaled by 1/SHARDS)
__global__ void bias_sum_kernel(const float* __restrict__ b, float* __restrict__ bsum) {
    int i = blockIdx.x * blockDim.x + threadIdx.x;
    if (i < OUT_DIM) {
        float s = 0.0f;
#pragma unroll
        for (int sh = 0; sh < SHARDS; ++sh) s += b[sh * OUT_DIM + i];
        bsum[i] = s * 0.125f;
    }
}

// Step 2: gather + fused bias/scale. Block b owns rows [16b, 16b+16); all 16
// token ids loaded to LDS before the loop so every gather address is known
// up-front. Thread t owns columns {c*1024 + t*4 .. +3 | c in 0..3}; output
// written with non-temporal stores (streamed-once, don't evict W from L2/L3).
__global__ __launch_bounds__(256) void embed_gather_kernel(
        const int* __restrict__ tok, const float* __restrict__ W,
        const float* __restrict__ bsum, float* __restrict__ out, int n) {
    const int t = threadIdx.x;  // 0..255
    __shared__ int ids[ROWS_PER_BLOCK];

    const int base = blockIdx.x * ROWS_PER_BLOCK;
    const int nrows = min(ROWS_PER_BLOCK, n - base);
    if (t < ROWS_PER_BLOCK && base + t < n) ids[t] = tok[base + t];

    const f32x4* bsum4 = reinterpret_cast<const f32x4*>(bsum);
    f32x4 bias[4];
#pragma unroll
    for (int c = 0; c < 4; ++c) bias[c] = bsum4[c * 256 + t];

    __syncthreads();

#pragma unroll 1
    for (int r = 0; r + 1 < nrows; r += 2) {
        const long long id0 = ids[r];
        const long long id1 = ids[r + 1];
        const f32x4* __restrict__ w0 =
            reinterpret_cast<const f32x4*>(W + id0 * (long long)OUT_DIM);
        const f32x4* __restrict__ w1 =
            reinterpret_cast<const f32x4*>(W + id1 * (long long)OUT_DIM);

        f32x4 a[4], d[4];
#pragma unroll
        for (int c = 0; c < 4; ++c) a[c] = w0[c * 256 + t];
#pragma unroll
        for (int c = 0; c < 4; ++c) d[c] = w1[c * 256 + t];

        f32x4* o0 = reinterpret_cast<f32x4*>(out + (long long)(base + r) * OUT_DIM);
        f32x4* o1 = reinterpret_cast<f32x4*>(out + (long long)(base + r + 1) * OUT_DIM);
#pragma unroll
        for (int c = 0; c < 4; ++c) {
            f32x4 v = a[c] * 0.125f + bias[c];
            __builtin_nontemporal_store(v, &o0[c * 256 + t]);
        }
#pragma unroll
        for (int c = 0; c < 4; ++c) {
            f32x4 v = d[c] * 0.125f + bias[c];
            __builtin_nontemporal_store(v, &o1[c * 256 + t]);
        }
    }
    // Odd tail row (n not multiple of 2 within this block)
    if (nrows & 1) {
        const int r = nrows - 1;
        const long long id0 = ids[r];
        const f32x4* __restrict__ w0 =
            reinterpret_cast<const f32x4*>(W + id0 * (long long)OUT_DIM);
        f32x4* o0 = reinterpret_cast<f32x4*>(out + (long long)(base + r) * OUT_DIM);
#pragma unroll
        for (int c = 0; c < 4; ++c) {
            f32x4 v = w0[c * 256 + t] * 0.125f + bias[c];
            __builtin_nontemporal_store(v, &o0[c * 256 + t]);
        }
    }
}

extern "C" void kernel_launch(void* const* d_in, const int* in_sizes, int n_in,
                              void* d_out, int out_size, void* d_ws, size_t ws_size,
                              hipStream_t stream) {
    const int*   tok = (const int*)d_in[0];
    const float* W   = (const float*)d_in[1];
    const float* b   = (const float*)d_in[2];
    float*       out = (float*)d_out;
    float*       bsum = (float*)d_ws;  // 4096 floats = 16 KB scratch

    const int n = in_sizes[0];  // 32768 tokens

    bias_sum_kernel<<<(OUT_DIM + 255) / 256, 256, 0, stream>>>(b, bsum);

    int grid = (n + ROWS_PER_BLOCK - 1) / ROWS_PER_BLOCK;  // 2048 blocks
    embed_gather_kernel<<<grid, 256, 0, stream>>>(tok, W, bsum, out, n);
}

// Round 4
// 169.600 us; speedup vs baseline: 1.0269x; 1.0269x over previous
//
#include <hip/hip_runtime.h>

// EmbeddingShard: out[n, :] = (W_full[tok[n], :] + sum_s b[s, :]) / SHARDS
// tok: [32768] int32, W: [8, 6300, 4096] f32 (contiguous == W_full [50400,4096]),
// b: [8, 4096] f32, out: [32768, 4096] f32.
// Memory-bound gather: ~537 MB streamed NT write + ~440 MB gather read.
// R4: R2 grid-stride structure (LDS preload reverted — R3 showed it neutral),
// deepened to 4 rows/iteration = 16 outstanding 16B gather loads per thread.

#define OUT_DIM 4096
#define SHARDS 8
#define RPI 4  // rows per iteration

typedef float f32x4 __attribute__((ext_vector_type(4)));

// Step 1: bsum[j] = (sum_s b[s][j]) * 0.125  (pre-scaled by 1/SHARDS)
__global__ void bias_sum_kernel(const float* __restrict__ b, float* __restrict__ bsum) {
    int i = blockIdx.x * blockDim.x + threadIdx.x;
    if (i < OUT_DIM) {
        float s = 0.0f;
#pragma unroll
        for (int sh = 0; sh < SHARDS; ++sh) s += b[sh * OUT_DIM + i];
        bsum[i] = s * 0.125f;
    }
}

// Step 2: gather + fused bias/scale. 256 threads/block; thread t owns columns
// {c*1024 + t*4 .. +3 | c in 0..3}. 4 rows per iteration: 4 independent id
// loads then 16 independent 16B gathers before any use. NT output stores keep
// the streamed-once output from evicting W-table lines in L2/L3.
__global__ __launch_bounds__(256) void embed_gather_kernel(
        const int* __restrict__ tok, const float* __restrict__ W,
        const float* __restrict__ bsum, float* __restrict__ out, int n) {
    const int t = threadIdx.x;  // 0..255
    const f32x4* bsum4 = reinterpret_cast<const f32x4*>(bsum);

    f32x4 bias[4];
#pragma unroll
    for (int c = 0; c < 4; ++c) bias[c] = bsum4[c * 256 + t];

    const int stride = gridDim.x * RPI;
    for (int row = blockIdx.x * RPI; row + RPI - 1 < n; row += stride) {
        long long id[RPI];
#pragma unroll
        for (int r = 0; r < RPI; ++r) id[r] = tok[row + r];

        f32x4 v[RPI][4];
#pragma unroll
        for (int r = 0; r < RPI; ++r) {
            const f32x4* __restrict__ wr =
                reinterpret_cast<const f32x4*>(W + id[r] * (long long)OUT_DIM);
#pragma unroll
            for (int c = 0; c < 4; ++c) v[r][c] = wr[c * 256 + t];
        }

#pragma unroll
        for (int r = 0; r < RPI; ++r) {
            f32x4* __restrict__ orow =
                reinterpret_cast<f32x4*>(out + (long long)(row + r) * OUT_DIM);
#pragma unroll
            for (int c = 0; c < 4; ++c) {
                f32x4 res = v[r][c] * 0.125f + bias[c];
                __builtin_nontemporal_store(res, &orow[c * 256 + t]);
            }
        }
    }

    // Tail rows (n not a multiple of RPI) — block 0 handles them serially.
    const int ntail = n & (RPI - 1);
    if (ntail && blockIdx.x == 0) {
        for (int row = n - ntail; row < n; ++row) {
            const long long id0 = tok[row];
            const f32x4* __restrict__ wr =
                reinterpret_cast<const f32x4*>(W + id0 * (long long)OUT_DIM);
            f32x4* __restrict__ orow =
                reinterpret_cast<f32x4*>(out + (long long)row * OUT_DIM);
#pragma unroll
            for (int c = 0; c < 4; ++c) {
                f32x4 res = wr[c * 256 + t] * 0.125f + bias[c];
                __builtin_nontemporal_store(res, &orow[c * 256 + t]);
            }
        }
    }
}

extern "C" void kernel_launch(void* const* d_in, const int* in_sizes, int n_in,
                              void* d_out, int out_size, void* d_ws, size_t ws_size,
                              hipStream_t stream) {
    const int*   tok = (const int*)d_in[0];
    const float* W   = (const float*)d_in[1];
    const float* b   = (const float*)d_in[2];
    float*       out = (float*)d_out;
    float*       bsum = (float*)d_ws;  // 4096 floats = 16 KB scratch

    const int n = in_sizes[0];  // 32768 tokens

    bias_sum_kernel<<<(OUT_DIM + 255) / 256, 256, 0, stream>>>(b, bsum);

    int groups = n / RPI;
    int grid = groups < 2048 ? (groups > 0 ? groups : 1) : 2048;
    embed_gather_kernel<<<grid, 256, 0, stream>>>(tok, W, bsum, out, n);
}